// Round 5
// baseline (3514.610 us; speedup 1.0000x reference)
//
#include <hip/hip_runtime.h>
#include <stdint.h>

#define NR 2048      // recurrent neurons
#define NI 256       // input channels
#define BB 64        // batch
#define TT 500       // timesteps
#define THREADS 1024

// ---------------------------------------------------------------------------
// Persistent per-batch LIF, exact float32 replica of the numpy reference.
// One workgroup per batch element; thread owns neurons tid and tid+1024.
//
// Exactness argument: numpy's z @ W_rec (sgemm) accumulates each output
// element k-ascending with a single accumulator; products z_j*w are exact
// (z binary), zero terms are exact no-ops. Hence the BLAS result equals an
// ordered f32 sum of W_rec[j][n] over active j ascending. Same for the
// x @ W_in einsum. We therefore keep a SORTED active list (ballot + prefix,
// fully deterministic) and gather dense rows in ascending j, accumulating
// with __fadd_rn (no FMA contraction, no reassociation).
// Update, separately rounded as numpy does it:
//   i_ff = ff + noise;  i_t = i_ff + rec;
//   v'   = ((DECAY_f32 * v) + i_t) - z;   z' = (v' > 1.0f)
// ---------------------------------------------------------------------------
__global__ __launch_bounds__(THREADS, 1) void lif_kernel(
    const float* __restrict__ x,      // [B,T,NI]
    const float* __restrict__ noise,  // [B,T,NR]
    const float* __restrict__ Win,    // [NI,NR]
    const float* __restrict__ Wrec,   // [NR,NR]
    float* __restrict__ outv,         // [B,T,NR]
    float* __restrict__ outz)         // [B,T,NR]
{
    const int b    = blockIdx.x;
    const int tid  = threadIdx.x;
    const int lane = tid & 63;
    const int wv   = tid >> 6;            // wave id 0..15
    const int n0   = tid;
    const int n1   = tid + THREADS;

    __shared__ unsigned long long msk[36];  // 0..15: z chunks 0..1023, 16..31: z chunks 1024..2047, 32..35: x chunks
    __shared__ int actS[NR];                // sorted active presyn neurons
    __shared__ int actX[NI];                // sorted active input channels

    // float32 rounding of exp(-1/20), as numpy applies it to an f32 array
    const float DECAYF = (float)0.9512294245007140090955600830807;

    const float* xb  = x     + (size_t)b * TT * NI;
    const float* nzb = noise + (size_t)b * TT * NR;
    float* vb = outv + (size_t)b * TT * NR;
    float* zb = outz + (size_t)b * TT * NR;

    const unsigned long long blw = (1ull << lane) - 1ull;

    float v0 = 0.f, v1 = 0.f, z0 = 0.f, z1 = 0.f;

    // ---- pre-loop: build sorted active-input list for x(0); z-lists empty ----
    float xq = (tid < NI) ? xb[tid] : 0.f;
    if (tid < 32) msk[tid] = 0ull;
    if (wv < 4) {
        const unsigned long long mx = __ballot(xq != 0.f);
        if (lane == 0) msk[32 + wv] = mx;
    }
    __syncthreads();
    int K = 0;
    int KX;
    {
        int sx = 0, offX = 0;
        #pragma unroll
        for (int c = 0; c < 4; ++c) {
            if (c == wv) offX = sx;
            sx += __popcll(msk[32 + c]);
        }
        KX = sx;
        if (tid < NI && xq != 0.f)
            actX[offX + __popcll(msk[32 + wv] & blw)] = tid;
    }
    __syncthreads();

    for (int t = 0; t < TT; ++t) {
        // prefetch next step's x
        float xn = 0.f;
        if (t + 1 < TT && tid < NI) xn = xb[(size_t)(t + 1) * NI + tid];
        const float na = nzb[(size_t)t * NR + n0];
        const float nb = nzb[(size_t)t * NR + n1];

        // feed-forward: ordered sum over active inputs (ascending i)
        float ff0 = 0.f, ff1 = 0.f;
        for (int k = 0; k < KX; ++k) {
            const int i = actX[k];
            const float* wr = Win + (size_t)i * NR;
            ff0 = __fadd_rn(ff0, wr[n0]);
            ff1 = __fadd_rn(ff1, wr[n1]);
        }
        // recurrent: ordered sum over active presyn neurons (ascending j)
        float r0 = 0.f, r1 = 0.f;
        for (int k = 0; k < K; ++k) {
            const int j = actS[k];
            const float* wr = Wrec + (size_t)j * NR;
            r0 = __fadd_rn(r0, wr[n0]);
            r1 = __fadd_rn(r1, wr[n1]);
        }

        const float it0 = __fadd_rn(__fadd_rn(ff0, na), r0);
        const float it1 = __fadd_rn(__fadd_rn(ff1, nb), r1);
        const float vn0 = __fsub_rn(__fadd_rn(__fmul_rn(DECAYF, v0), it0), z0);
        const float vn1 = __fsub_rn(__fadd_rn(__fmul_rn(DECAYF, v1), it1), z1);
        const float zn0 = (vn0 > 1.0f) ? 1.0f : 0.0f;
        const float zn1 = (vn1 > 1.0f) ? 1.0f : 0.0f;

        const size_t o = (size_t)t * NR;
        vb[o + n0] = vn0; vb[o + n1] = vn1;
        zb[o + n0] = zn0; zb[o + n1] = zn1;

        // ballots for next step's sorted lists
        const unsigned long long m0 = __ballot(zn0 != 0.f);
        const unsigned long long m1 = __ballot(zn1 != 0.f);
        if (lane == 0) { msk[wv] = m0; msk[16 + wv] = m1; }
        if (wv < 4) {
            const unsigned long long mx = __ballot(xn != 0.f);
            if (lane == 0) msk[32 + wv] = mx;
        }
        __syncthreads();   // masks visible; actS/actX fully consumed above

        // per-thread exclusive prefix over chunk popcounts (deterministic)
        int s = 0, offA = 0, offB = 0;
        #pragma unroll
        for (int c = 0; c < 32; ++c) {
            if (c == wv)      offA = s;
            if (c == 16 + wv) offB = s;
            s += __popcll(msk[c]);
        }
        K = s;
        int sx = 0, offX = 0;
        #pragma unroll
        for (int c = 0; c < 4; ++c) {
            if (c == wv) offX = sx;
            sx += __popcll(msk[32 + c]);
        }
        KX = sx;

        if (zn0 != 0.f) actS[offA + __popcll(msk[wv]      & blw)] = n0;
        if (zn1 != 0.f) actS[offB + __popcll(msk[16 + wv] & blw)] = n1;
        if (tid < NI && xn != 0.f) actX[offX + __popcll(msk[32 + wv] & blw)] = tid;
        __syncthreads();   // lists visible for next iteration

        v0 = vn0; v1 = vn1; z0 = zn0; z1 = zn1;
    }
}

extern "C" void kernel_launch(void* const* d_in, const int* in_sizes, int n_in,
                              void* d_out, int out_size, void* d_ws, size_t ws_size,
                              hipStream_t stream) {
    const float* x     = (const float*)d_in[0];
    const float* noise = (const float*)d_in[1];
    const float* Win   = (const float*)d_in[2];
    const float* Wrec  = (const float*)d_in[3];
    float* outv = (float*)d_out;
    float* outz = outv + (size_t)BB * TT * NR;

    hipLaunchKernelGGL(lif_kernel, dim3(BB), dim3(THREADS), 0, stream,
                       x, noise, Win, Wrec, outv, outz);
}